// Round 2
// baseline (3559.238 us; speedup 1.0000x reference)
//
#include <hip/hip_runtime.h>
#include <stdint.h>

// RNN_60292750901480: h_t = tanh(x_t@Wx + b + h_{t-1}@Wh), N=128,T=512,D=H=512, fp32.
// Phase 1: xW = x@Wx+b via split-bf16 MFMA (fp32-quality) into d_out. (unchanged)
// Phase 2: persistent kernel, 8 row-clusters x 16 col-blocks, Wh B-frags in VGPRs.
// R3 -> R4: flag elimination. R3's publish path was two serialized cross-die round
// trips: [stores -> vmcnt(0) drain -> barrier -> tid0 flag store] then consumer
// [flag poll hop -> data load hop]. Now every mailbox element is a self-validating
// u64 {packed bf16hi|lo, step tag} stored with one relaxed agent-scope atomic:
// producer publishes straight out of tanh (no drain/barrier/flag), consumer's
// detecting load IS the data load (one hop). Ring safety: tag t seen on chunk s
// => block s passed its iter t-1 barrier => its reads of h_{t-2} (the plane being
// overwritten) completed; each block confirms all 16 chunks across its 4 waves
// before its own barrier-then-store. Second barrier removed via parity-double-
// buffered LDS reduce. Arithmetic bit-identical to R3.

typedef __attribute__((ext_vector_type(8))) short short8;
typedef __attribute__((ext_vector_type(4))) float f32x4;

#define DEV static __device__ __forceinline__

DEV unsigned short f2bf(float f) {
    uint32_t u = __builtin_bit_cast(uint32_t, f);
    u += 0x7FFFu + ((u >> 16) & 1u);   // round-to-nearest-even
    return (unsigned short)(u >> 16);
}
DEV float bf2f(unsigned short h) {
    uint32_t u = ((uint32_t)h) << 16;
    return __builtin_bit_cast(float, u);
}
DEV void split8(const float* v, short8& hi, short8& lo) {
    #pragma unroll
    for (int j = 0; j < 8; ++j) {
        unsigned short h = f2bf(v[j]);
        float r = v[j] - bf2f(h);       // exact
        hi[j] = (short)h;
        lo[j] = (short)f2bf(r);
    }
}
DEV uint32_t packsplit(float v) {
    unsigned short h = f2bf(v);
    float r = v - bf2f(h);              // exact
    return (uint32_t)h | ((uint32_t)f2bf(r) << 16);
}
DEV uint64_t cohload64(const uint64_t* p) {
    return __hip_atomic_load(p, __ATOMIC_RELAXED, __HIP_MEMORY_SCOPE_AGENT);
}
DEV void cohstore64(uint64_t* p, uint64_t v) {
    __hip_atomic_store(p, v, __ATOMIC_RELAXED, __HIP_MEMORY_SCOPE_AGENT);
}

// ---------------- Phase 1: xW = x @ Wx + b  (M=65536, K=512, N=512) ----------------
__global__ __launch_bounds__(256) void xw_gemm(
    const float* __restrict__ x, const float* __restrict__ Wx,
    const float* __restrict__ bias, float* __restrict__ out)
{
    __shared__ short Ahi[128 * 32], Alo[128 * 32];
    __shared__ short Bhi[32 * 128], Blo[32 * 128];

    const int bid = blockIdx.x;
    const int m0 = (bid >> 2) * 128;
    const int n0 = (bid & 3) * 128;
    const int tid = threadIdx.x;
    const int lane = tid & 63;
    const int wave = tid >> 6;
    const int wr = (wave >> 1) * 64;
    const int wc = (wave & 1) * 64;

    f32x4 acc[4][4];
    #pragma unroll
    for (int i = 0; i < 4; ++i)
        #pragma unroll
        for (int j = 0; j < 4; ++j)
            acc[i][j] = (f32x4){0.f, 0.f, 0.f, 0.f};

    for (int kc = 0; kc < 512; kc += 32) {
        __syncthreads();
        #pragma unroll
        for (int cc = 0; cc < 2; ++cc) {
            int c = tid + cc * 256;
            int row = c >> 2, kb = c & 3;
            const float* src = x + (size_t)(m0 + row) * 512 + kc + kb * 8;
            alignas(16) float v[8];
            *(float4*)(v)     = *(const float4*)src;
            *(float4*)(v + 4) = *(const float4*)(src + 4);
            short8 h8, l8;
            split8(v, h8, l8);
            int cell = ((row >> 4) * 4 + kb) * 16 + (row & 15);
            *(short8*)&Ahi[cell * 8] = h8;
            *(short8*)&Alo[cell * 8] = l8;
        }
        {
            int cell = tid >> 3, j = tid & 7;
            int ct = cell >> 2, kb = cell & 3;
            const float* src = Wx + (size_t)(kc + kb * 8 + j) * 512 + n0 + ct * 16;
            #pragma unroll
            for (int c16 = 0; c16 < 16; ++c16) {
                float v = src[c16];
                unsigned short h = f2bf(v);
                int idx = (cell * 16 + c16) * 8 + j;
                Bhi[idx] = (short)h;
                Blo[idx] = (short)f2bf(v - bf2f(h));
            }
        }
        __syncthreads();

        short8 bh[4], bl[4];
        #pragma unroll
        for (int ct = 0; ct < 4; ++ct) {
            int CT = (wc >> 4) + ct;
            bh[ct] = *(const short8*)&Bhi[CT * 512 + lane * 8];
            bl[ct] = *(const short8*)&Blo[CT * 512 + lane * 8];
        }
        #pragma unroll
        for (int rt = 0; rt < 4; ++rt) {
            int RT = (wr >> 4) + rt;
            short8 ah = *(const short8*)&Ahi[RT * 512 + lane * 8];
            short8 al = *(const short8*)&Alo[RT * 512 + lane * 8];
            #pragma unroll
            for (int ct = 0; ct < 4; ++ct) {
                acc[rt][ct] = __builtin_amdgcn_mfma_f32_16x16x32_bf16(ah, bh[ct], acc[rt][ct], 0, 0, 0);
                acc[rt][ct] = __builtin_amdgcn_mfma_f32_16x16x32_bf16(al, bh[ct], acc[rt][ct], 0, 0, 0);
                acc[rt][ct] = __builtin_amdgcn_mfma_f32_16x16x32_bf16(ah, bl[ct], acc[rt][ct], 0, 0, 0);
            }
        }
    }
    #pragma unroll
    for (int ct = 0; ct < 4; ++ct) {
        int col = n0 + wc + ct * 16 + (lane & 15);
        float bv = bias[col];
        #pragma unroll
        for (int rt = 0; rt < 4; ++rt) {
            int rbase = m0 + wr + rt * 16 + (lane >> 4) * 4;
            #pragma unroll
            for (int j = 0; j < 4; ++j)
                out[(size_t)(rbase + j) * 512 + col] = acc[rt][ct][j] + bv;
        }
    }
}

// ---------------- Phase 2: persistent recurrence ----------------
// 128 wgs: cluster r = b&7 (16 batch rows), col-block c = b>>3 (32 cols).
// 4 waves k-split 128 each; Wh hi/lo B-frags resident in VGPRs.
//
// Mailbox: 2 parity planes x 128 chunks x 512 u64. Chunk c = r*16 + cblk holds the
// producer's 16x32 h-tile; element u64 = {lo32: bf16hi|bf16lo<<16, hi32: step tag}.
// Layout: u64 idx within chunk = j*64 + l,  l = (col>>3)*16 + row, j = col&7 —
// exactly the MFMA A-fragment order, so consumer instruction i of chunk s is a
// fully coalesced load of u64 idx = chunk*512 + i*64 + lane (64 lanes x 8B).
// h_t goes to plane t&1 with tag t+1; consumer at iter t polls plane (t-1)&1
// for tag == t. Tags are monotone -> poison/replay-proof; plane parity means
// residual tags from a previous run/step never alias the current target.
__global__ __launch_bounds__(256) void rnn_scan(
    float* xw_out,                      // d_out: xW in, h out (aliased by design)
    const float* __restrict__ h0,
    const float* __restrict__ Wh,
    uint64_t* __restrict__ hpk)         // [2][128 chunks][512] tagged mailbox in d_ws
{
    const int b = blockIdx.x;
    const int r = b & 7;
    const int cblk = b >> 3;
    const int tid = threadIdx.x;
    const int lane = tid & 63;
    const int wave = tid >> 6;
    const int m0 = r * 16;
    const int n0 = cblk * 32;
    const int k0 = wave * 128;

    // Preload Wh B-fragments (hi/lo), resident across all 512 steps.
    short8 Bh[4][2], Bl[4][2];
    #pragma unroll
    for (int s = 0; s < 4; ++s) {
        #pragma unroll
        for (int ct = 0; ct < 2; ++ct) {
            int col = n0 + ct * 16 + (lane & 15);
            #pragma unroll
            for (int j = 0; j < 8; ++j) {
                int k = k0 + s * 32 + (lane >> 4) * 8 + j;
                float v = Wh[(size_t)k * 512 + col];
                unsigned short h = f2bf(v);
                Bh[s][ct][j] = (short)h;
                Bl[s][ct][j] = (short)f2bf(v - bf2f(h));
            }
        }
    }

    // Parity-double-buffered k-split partials: [par][wave][coltile][row][col] (16 KiB)
    __shared__ float red[2][4][2][16][16];

    const int erow = tid >> 5;           // 0..7
    const int ecol = tid & 31;           // 0..31
    const int arow = lane & 15, akb = lane >> 4;

    // Producer-side mailbox addressing (this block's chunk, both parities).
    uint64_t* ch0 = hpk + (size_t)(r * 16 + cblk) * 512;
    uint64_t* ch1 = ch0 + 65536;
    const int pidx = (ecol & 7) * 64 + (ecol >> 3) * 16 + erow;

    // Consumer-side bases: wave w reads chunks r*16 + w*4 + s, s=0..3.
    const uint64_t* qb0 = hpk + (size_t)(r * 16 + wave * 4) * 512 + lane;
    const uint64_t* qb1 = qb0 + 65536;

    for (int t = 0; t < 512; ++t) {
        // This step's xW tile (plain cached loads; wg-private slice). Issued
        // before the poll so HBM latency overlaps the wait.
        size_t xi0 = ((size_t)(m0 + erow) * 512 + t) * 512 + n0 + ecol;
        size_t xi1 = ((size_t)(m0 + 8 + erow) * 512 + t) * 512 + n0 + ecol;
        float xw0 = xw_out[xi0];
        float xw1 = xw_out[xi1];

        f32x4 acc0 = (f32x4){0.f, 0.f, 0.f, 0.f};
        f32x4 acc1 = (f32x4){0.f, 0.f, 0.f, 0.f};

        if (t == 0) {
            // h0 is read-only fp32: plain vector loads + one-time split.
            #pragma unroll
            for (int s = 0; s < 4; ++s) {
                alignas(16) float hv[8];
                const float* ap = h0 + (size_t)(m0 + arow) * 512 + k0 + s * 32 + akb * 8;
                *(float4*)(hv)     = *(const float4*)ap;
                *(float4*)(hv + 4) = *(const float4*)(ap + 4);
                short8 ah, al;
                split8(hv, ah, al);
                acc0 = __builtin_amdgcn_mfma_f32_16x16x32_bf16(ah, Bh[s][0], acc0, 0, 0, 0);
                acc0 = __builtin_amdgcn_mfma_f32_16x16x32_bf16(al, Bh[s][0], acc0, 0, 0, 0);
                acc0 = __builtin_amdgcn_mfma_f32_16x16x32_bf16(ah, Bl[s][0], acc0, 0, 0, 0);
                acc1 = __builtin_amdgcn_mfma_f32_16x16x32_bf16(ah, Bh[s][1], acc1, 0, 0, 0);
                acc1 = __builtin_amdgcn_mfma_f32_16x16x32_bf16(al, Bh[s][1], acc1, 0, 0, 0);
                acc1 = __builtin_amdgcn_mfma_f32_16x16x32_bf16(ah, Bl[s][1], acc1, 0, 0, 0);
            }
        } else {
            const uint64_t* qc = ((t - 1) & 1) ? qb1 : qb0;
            const uint32_t tgt = (uint32_t)t;

            // Speculatively issue all 32 tagged loads (one latency for the
            // common case), then finalize per chunk so ready chunks' MFMA
            // overlaps waiting for late producers.
            uint64_t q[4][8];
            #pragma unroll
            for (int s = 0; s < 4; ++s)
                #pragma unroll
                for (int i = 0; i < 8; ++i)
                    q[s][i] = cohload64(qc + s * 512 + i * 64);

            #pragma unroll
            for (int s = 0; s < 4; ++s) {
                for (;;) {
                    uint32_t bad = 0;
                    #pragma unroll
                    for (int i = 0; i < 8; ++i)
                        bad |= (uint32_t)((uint32_t)(q[s][i] >> 32) != tgt);
                    if (__all(bad == 0)) break;
                    __builtin_amdgcn_s_sleep(1);
                    #pragma unroll
                    for (int i = 0; i < 8; ++i)
                        if ((uint32_t)(q[s][i] >> 32) != tgt)
                            q[s][i] = cohload64(qc + s * 512 + i * 64);
                }
                short8 ah, al;
                #pragma unroll
                for (int i = 0; i < 8; ++i) {
                    uint32_t v = (uint32_t)q[s][i];
                    ah[i] = (short)(v & 0xffffu);
                    al[i] = (short)(v >> 16);
                }
                acc0 = __builtin_amdgcn_mfma_f32_16x16x32_bf16(ah, Bh[s][0], acc0, 0, 0, 0);
                acc0 = __builtin_amdgcn_mfma_f32_16x16x32_bf16(al, Bh[s][0], acc0, 0, 0, 0);
                acc0 = __builtin_amdgcn_mfma_f32_16x16x32_bf16(ah, Bl[s][0], acc0, 0, 0, 0);
                acc1 = __builtin_amdgcn_mfma_f32_16x16x32_bf16(ah, Bh[s][1], acc1, 0, 0, 0);
                acc1 = __builtin_amdgcn_mfma_f32_16x16x32_bf16(al, Bh[s][1], acc1, 0, 0, 0);
                acc1 = __builtin_amdgcn_mfma_f32_16x16x32_bf16(ah, Bl[s][1], acc1, 0, 0, 0);
            }
        }

        // k-split reduction across the 4 waves via parity-buffered LDS.
        const int par = t & 1;
        #pragma unroll
        for (int ct = 0; ct < 2; ++ct) {
            f32x4 a = ct ? acc1 : acc0;
            #pragma unroll
            for (int j = 0; j < 4; ++j)
                red[par][wave][ct][(lane >> 4) * 4 + j][lane & 15] = a[j];
        }
        __syncthreads();   // the ONLY barrier per step (joins polls + reduce)

        int ctt = ecol >> 4, c16 = ecol & 31 & 15;
        float sum0 = red[par][0][ctt][erow][c16] + red[par][1][ctt][erow][c16]
                   + red[par][2][ctt][erow][c16] + red[par][3][ctt][erow][c16];
        float sum1 = red[par][0][ctt][erow + 8][c16] + red[par][1][ctt][erow + 8][c16]
                   + red[par][2][ctt][erow + 8][c16] + red[par][3][ctt][erow + 8][c16];

        // Publish straight out of tanh: tagged, self-validating stores.
        uint64_t* ch = par ? ch1 : ch0;
        const uint64_t tag = ((uint64_t)(unsigned)(t + 1)) << 32;
        float hv0 = tanhf(xw0 + sum0);
        cohstore64(&ch[pidx], (uint64_t)packsplit(hv0) | tag);
        float hv1 = tanhf(xw1 + sum1);
        cohstore64(&ch[pidx + 8], (uint64_t)packsplit(hv1) | tag);

        // Final output [N,T,H] (plain, nobody reads it) — off the publish path.
        xw_out[xi0] = hv0;
        xw_out[xi1] = hv1;
    }
}

extern "C" void kernel_launch(void* const* d_in, const int* in_sizes, int n_in,
                              void* d_out, int out_size, void* d_ws, size_t ws_size,
                              hipStream_t stream)
{
    const float* x  = (const float*)d_in[0];
    const float* h0 = (const float*)d_in[1];
    const float* Wx = (const float*)d_in[2];
    const float* Wh = (const float*)d_in[3];
    const float* b  = (const float*)d_in[4];
    float* out = (float*)d_out;

    uint64_t* hpk = (uint64_t*)d_ws;   // 2 planes x 128 chunks x 512 u64 = 1 MiB

    hipLaunchKernelGGL(xw_gemm, dim3(2048), dim3(256), 0, stream, x, Wx, b, out);
    hipLaunchKernelGGL(rnn_scan, dim3(128), dim3(256), 0, stream, out, h0, Wh, hpk);
}

// Round 4
// 2810.188 us; speedup vs baseline: 1.2665x; 1.2665x over previous
//
#include <hip/hip_runtime.h>
#include <stdint.h>

// RNN_60292750901480: h_t = tanh(x_t@Wx + b + h_{t-1}@Wh), N=128,T=512,D=H=512, fp32.
// Phase 1: xW = x@Wx+b via split-bf16 MFMA (fp32-quality) into d_out. (unchanged)
// Phase 2: persistent kernel, 8 row-clusters x 16 col-blocks, Wh B-frags in VGPRs.
//
// R5 -> R6: R5 (same-XCD L2 fast path) died with no counters -- hang or compile
// failure, all candidate causes in the unproven fast path (sc0 load semantics,
// 16-operand tied asm, s_getreg). R6 re-establishes a working baseline carrying
// only the structurally-sound R5 improvements, in proven primitives:
//   * per-wave subflags posted after a wave-local vmcnt(0) drain (kills R3's
//     block-drain -> tid0-flag tail),
//   * per-wave polling of exactly the 16 subflags covering that wave's 4 chunks,
//     with data loads issued immediately after (kills R3's poll->barrier hop),
//   * parity-double-buffered LDS reduce (one barrier/step, validated in R4).
// All communication stays agent-scope (placement-safe). Release safety: a block's
// plane-par stores are post-barrier; the barrier joins 4 waves whose polls saw all
// 16 members x 4 waves at flag==t, each posted only after that wave's reads of the
// plane being overwritten completed. Arithmetic bit-identical to R3.

typedef __attribute__((ext_vector_type(8))) short short8;
typedef __attribute__((ext_vector_type(4))) float f32x4;

#define DEV static __device__ __forceinline__

DEV unsigned short f2bf(float f) {
    uint32_t u = __builtin_bit_cast(uint32_t, f);
    u += 0x7FFFu + ((u >> 16) & 1u);   // round-to-nearest-even
    return (unsigned short)(u >> 16);
}
DEV float bf2f(unsigned short h) {
    uint32_t u = ((uint32_t)h) << 16;
    return __builtin_bit_cast(float, u);
}
DEV void split8(const float* v, short8& hi, short8& lo) {
    #pragma unroll
    for (int j = 0; j < 8; ++j) {
        unsigned short h = f2bf(v[j]);
        float r = v[j] - bf2f(h);       // exact
        hi[j] = (short)h;
        lo[j] = (short)f2bf(r);
    }
}
DEV uint32_t packsplit(float v) {
    unsigned short h = f2bf(v);
    float r = v - bf2f(h);              // exact
    return (uint32_t)h | ((uint32_t)f2bf(r) << 16);
}
DEV uint64_t cohload64(const uint64_t* p) {
    return __hip_atomic_load(p, __ATOMIC_RELAXED, __HIP_MEMORY_SCOPE_AGENT);
}

// ---------------- Phase 1: xW = x @ Wx + b  (M=65536, K=512, N=512) ----------------
__global__ __launch_bounds__(256) void xw_gemm(
    const float* __restrict__ x, const float* __restrict__ Wx,
    const float* __restrict__ bias, float* __restrict__ out)
{
    __shared__ short Ahi[128 * 32], Alo[128 * 32];
    __shared__ short Bhi[32 * 128], Blo[32 * 128];

    const int bid = blockIdx.x;
    const int m0 = (bid >> 2) * 128;
    const int n0 = (bid & 3) * 128;
    const int tid = threadIdx.x;
    const int lane = tid & 63;
    const int wave = tid >> 6;
    const int wr = (wave >> 1) * 64;
    const int wc = (wave & 1) * 64;

    f32x4 acc[4][4];
    #pragma unroll
    for (int i = 0; i < 4; ++i)
        #pragma unroll
        for (int j = 0; j < 4; ++j)
            acc[i][j] = (f32x4){0.f, 0.f, 0.f, 0.f};

    for (int kc = 0; kc < 512; kc += 32) {
        __syncthreads();
        #pragma unroll
        for (int cc = 0; cc < 2; ++cc) {
            int c = tid + cc * 256;
            int row = c >> 2, kb = c & 3;
            const float* src = x + (size_t)(m0 + row) * 512 + kc + kb * 8;
            alignas(16) float v[8];
            *(float4*)(v)     = *(const float4*)src;
            *(float4*)(v + 4) = *(const float4*)(src + 4);
            short8 h8, l8;
            split8(v, h8, l8);
            int cell = ((row >> 4) * 4 + kb) * 16 + (row & 15);
            *(short8*)&Ahi[cell * 8] = h8;
            *(short8*)&Alo[cell * 8] = l8;
        }
        {
            int cell = tid >> 3, j = tid & 7;
            int ct = cell >> 2, kb = cell & 3;
            const float* src = Wx + (size_t)(kc + kb * 8 + j) * 512 + n0 + ct * 16;
            #pragma unroll
            for (int c16 = 0; c16 < 16; ++c16) {
                float v = src[c16];
                unsigned short h = f2bf(v);
                int idx = (cell * 16 + c16) * 8 + j;
                Bhi[idx] = (short)h;
                Blo[idx] = (short)f2bf(v - bf2f(h));
            }
        }
        __syncthreads();

        short8 bh[4], bl[4];
        #pragma unroll
        for (int ct = 0; ct < 4; ++ct) {
            int CT = (wc >> 4) + ct;
            bh[ct] = *(const short8*)&Bhi[CT * 512 + lane * 8];
            bl[ct] = *(const short8*)&Blo[CT * 512 + lane * 8];
        }
        #pragma unroll
        for (int rt = 0; rt < 4; ++rt) {
            int RT = (wr >> 4) + rt;
            short8 ah = *(const short8*)&Ahi[RT * 512 + lane * 8];
            short8 al = *(const short8*)&Alo[RT * 512 + lane * 8];
            #pragma unroll
            for (int ct = 0; ct < 4; ++ct) {
                acc[rt][ct] = __builtin_amdgcn_mfma_f32_16x16x32_bf16(ah, bh[ct], acc[rt][ct], 0, 0, 0);
                acc[rt][ct] = __builtin_amdgcn_mfma_f32_16x16x32_bf16(al, bh[ct], acc[rt][ct], 0, 0, 0);
                acc[rt][ct] = __builtin_amdgcn_mfma_f32_16x16x32_bf16(ah, bl[ct], acc[rt][ct], 0, 0, 0);
            }
        }
    }
    #pragma unroll
    for (int ct = 0; ct < 4; ++ct) {
        int col = n0 + wc + ct * 16 + (lane & 15);
        float bv = bias[col];
        #pragma unroll
        for (int rt = 0; rt < 4; ++rt) {
            int rbase = m0 + wr + rt * 16 + (lane >> 4) * 4;
            #pragma unroll
            for (int j = 0; j < 4; ++j)
                out[(size_t)(rbase + j) * 512 + col] = acc[rt][ct][j] + bv;
        }
    }
}

// ---------------- Phase 2: persistent recurrence ----------------
// Mailbox: 2 parity planes x 128 chunks x 512 u32 (R3 layout, bit-identical).
// Subflag ring: [slot 0..15][r 0..7][cblk 0..15][wave 0..3] u32, value t+1,
// equality compare (monotonic -> poison/replay-proof; 16-deep slots never alias).
// Consumer wave w's 16 needed subflags (producers 4w..4w+3, x4 waves) are one
// contiguous 64B line at slot*512 + r*64 + w*16.
__global__ __launch_bounds__(256) void rnn_scan(
    float* xw_out,                      // d_out: xW in, h out (aliased by design)
    const float* __restrict__ h0,
    const float* __restrict__ Wh,
    uint32_t* __restrict__ hpk,         // [2][128 chunks][512] packed planes
    uint32_t* __restrict__ flags)       // [16][8][16][4] agent subflag ring
{
    const int b = blockIdx.x;
    const int r = b & 7;
    const int cblk = b >> 3;
    const int tid = threadIdx.x;
    const int lane = tid & 63;
    const int wave = tid >> 6;
    const int m0 = r * 16;
    const int n0 = cblk * 32;
    const int k0 = wave * 128;

    // Preload Wh B-fragments (hi/lo), resident across all 512 steps.
    short8 Bh[4][2], Bl[4][2];
    #pragma unroll
    for (int s = 0; s < 4; ++s) {
        #pragma unroll
        for (int ct = 0; ct < 2; ++ct) {
            int col = n0 + ct * 16 + (lane & 15);
            #pragma unroll
            for (int j = 0; j < 8; ++j) {
                int k = k0 + s * 32 + (lane >> 4) * 8 + j;
                float v = Wh[(size_t)k * 512 + col];
                unsigned short h = f2bf(v);
                Bh[s][ct][j] = (short)h;
                Bl[s][ct][j] = (short)f2bf(v - bf2f(h));
            }
        }
    }

    // Parity-double-buffered k-split partials (16 KiB).
    __shared__ float red[2][4][2][16][16];

    const int erow = tid >> 5;           // 0..7
    const int ecol = tid & 31;           // 0..31
    const int arow = lane & 15, akb = lane >> 4;

    // Producer-side mailbox addressing (this block's chunk, both parities).
    uint32_t* ch0 = hpk + (size_t)(r * 16 + cblk) * 512;
    uint32_t* ch1 = ch0 + 65536;
    const int pidx = ((ecol >> 1) & 3) * 128
                   + (((ecol >> 3) & 3) * 16 + erow) * 2 + (ecol & 1);

    // Consumer-side bases: wave w reads chunks r*16 + w*4 + s, s=0..3.
    const uint64_t* qb0 = (const uint64_t*)hpk + (size_t)(r * 16 + wave * 4) * 256 + lane;
    const uint64_t* qb1 = qb0 + 32768;

    // This wave's subflag index for step t: (t&15)*512 + r*64 + cblk*4 + wave.
    const int myflag = r * 64 + cblk * 4 + wave;

    for (int t = 0; t < 512; ++t) {
        // This step's xW tile (plain cached loads; wg-private slice), issued
        // before the poll so HBM latency overlaps the wait.
        size_t xi0 = ((size_t)(m0 + erow) * 512 + t) * 512 + n0 + ecol;
        size_t xi1 = ((size_t)(m0 + 8 + erow) * 512 + t) * 512 + n0 + ecol;
        float xw0 = xw_out[xi0];
        float xw1 = xw_out[xi1];

        f32x4 acc0 = (f32x4){0.f, 0.f, 0.f, 0.f};
        f32x4 acc1 = (f32x4){0.f, 0.f, 0.f, 0.f};

        if (t == 0) {
            // h0 is read-only fp32: plain vector loads + one-time split.
            #pragma unroll
            for (int s = 0; s < 4; ++s) {
                alignas(16) float hv[8];
                const float* ap = h0 + (size_t)(m0 + arow) * 512 + k0 + s * 32 + akb * 8;
                *(float4*)(hv)     = *(const float4*)ap;
                *(float4*)(hv + 4) = *(const float4*)(ap + 4);
                short8 ah, al;
                split8(hv, ah, al);
                acc0 = __builtin_amdgcn_mfma_f32_16x16x32_bf16(ah, Bh[s][0], acc0, 0, 0, 0);
                acc0 = __builtin_amdgcn_mfma_f32_16x16x32_bf16(al, Bh[s][0], acc0, 0, 0, 0);
                acc0 = __builtin_amdgcn_mfma_f32_16x16x32_bf16(ah, Bl[s][0], acc0, 0, 0, 0);
                acc1 = __builtin_amdgcn_mfma_f32_16x16x32_bf16(ah, Bh[s][1], acc1, 0, 0, 0);
                acc1 = __builtin_amdgcn_mfma_f32_16x16x32_bf16(al, Bh[s][1], acc1, 0, 0, 0);
                acc1 = __builtin_amdgcn_mfma_f32_16x16x32_bf16(ah, Bl[s][1], acc1, 0, 0, 0);
            }
        } else {
            // Per-wave poll: the 16 subflags covering this wave's 4 chunks.
            {
                const uint32_t* fp =
                    flags + (size_t)((t - 1) & 15) * 512 + r * 64 + wave * 16 + lane;
                bool ok = (lane >= 16);
                for (;;) {
                    if (!ok)
                        ok = (__hip_atomic_load(fp, __ATOMIC_RELAXED,
                                                __HIP_MEMORY_SCOPE_AGENT) == (uint32_t)t);
                    if (__all((int)ok)) break;
                    __builtin_amdgcn_s_sleep(1);
                }
            }

            // 16 coalesced u64 coherent loads (one batch, one drain).
            const uint64_t* qc = ((t - 1) & 1) ? qb1 : qb0;
            uint64_t q[4][4];
            #pragma unroll
            for (int s = 0; s < 4; ++s)
                #pragma unroll
                for (int i = 0; i < 4; ++i)
                    q[s][i] = cohload64(qc + s * 256 + i * 64);

            #pragma unroll
            for (int s = 0; s < 4; ++s) {
                short8 ah, al;
                #pragma unroll
                for (int i = 0; i < 4; ++i) {
                    uint32_t u0 = (uint32_t)q[s][i];
                    uint32_t u1 = (uint32_t)(q[s][i] >> 32);
                    ah[2 * i]     = (short)(u0 & 0xffffu);
                    al[2 * i]     = (short)(u0 >> 16);
                    ah[2 * i + 1] = (short)(u1 & 0xffffu);
                    al[2 * i + 1] = (short)(u1 >> 16);
                }
                acc0 = __builtin_amdgcn_mfma_f32_16x16x32_bf16(ah, Bh[s][0], acc0, 0, 0, 0);
                acc0 = __builtin_amdgcn_mfma_f32_16x16x32_bf16(al, Bh[s][0], acc0, 0, 0, 0);
                acc0 = __builtin_amdgcn_mfma_f32_16x16x32_bf16(ah, Bl[s][0], acc0, 0, 0, 0);
                acc1 = __builtin_amdgcn_mfma_f32_16x16x32_bf16(ah, Bh[s][1], acc1, 0, 0, 0);
                acc1 = __builtin_amdgcn_mfma_f32_16x16x32_bf16(al, Bh[s][1], acc1, 0, 0, 0);
                acc1 = __builtin_amdgcn_mfma_f32_16x16x32_bf16(ah, Bl[s][1], acc1, 0, 0, 0);
            }
        }

        // k-split reduction across the 4 waves via parity-buffered LDS.
        const int par = t & 1;
        #pragma unroll
        for (int ct = 0; ct < 2; ++ct) {
            f32x4 a = ct ? acc1 : acc0;
            #pragma unroll
            for (int j = 0; j < 4; ++j)
                red[par][wave][ct][(lane >> 4) * 4 + j][lane & 15] = a[j];
        }
        __syncthreads();   // the ONLY barrier per step (joins polls + reduce)

        int ctt = ecol >> 4, c16 = ecol & 15;
        float sum0 = red[par][0][ctt][erow][c16] + red[par][1][ctt][erow][c16]
                   + red[par][2][ctt][erow][c16] + red[par][3][ctt][erow][c16];
        float sum1 = red[par][0][ctt][erow + 8][c16] + red[par][1][ctt][erow + 8][c16]
                   + red[par][2][ctt][erow + 8][c16] + red[par][3][ctt][erow + 8][c16];
        float hv0 = tanhf(xw0 + sum0);
        float hv1 = tanhf(xw1 + sum1);

        // Publish h tile (agent scope), then wave-local drain + per-wave subflag.
        uint32_t* ch = par ? ch1 : ch0;
        __hip_atomic_store(&ch[pidx], packsplit(hv0), __ATOMIC_RELAXED,
                           __HIP_MEMORY_SCOPE_AGENT);
        __hip_atomic_store(&ch[pidx + 16], packsplit(hv1), __ATOMIC_RELAXED,
                           __HIP_MEMORY_SCOPE_AGENT);
        // This wave's data stores reach the coherence point before its subflag.
        asm volatile("s_waitcnt vmcnt(0)" ::: "memory");
        if (lane == 0)
            __hip_atomic_store(&flags[(size_t)(t & 15) * 512 + myflag],
                               (uint32_t)(t + 1), __ATOMIC_RELAXED,
                               __HIP_MEMORY_SCOPE_AGENT);

        // Final output [N,T,H] (plain, nobody reads it) — off the publish path.
        xw_out[xi0] = hv0;
        xw_out[xi1] = hv1;
    }
}

extern "C" void kernel_launch(void* const* d_in, const int* in_sizes, int n_in,
                              void* d_out, int out_size, void* d_ws, size_t ws_size,
                              hipStream_t stream)
{
    const float* x  = (const float*)d_in[0];
    const float* h0 = (const float*)d_in[1];
    const float* Wx = (const float*)d_in[2];
    const float* Wh = (const float*)d_in[3];
    const float* b  = (const float*)d_in[4];
    float* out = (float*)d_out;

    uint32_t* hpk   = (uint32_t*)d_ws;         // 512 KiB mailbox (2 planes)
    uint32_t* flags = hpk + 2 * 65536;         // 32 KiB subflag ring

    hipLaunchKernelGGL(xw_gemm, dim3(2048), dim3(256), 0, stream, x, Wx, b, out);
    hipLaunchKernelGGL(rnn_scan, dim3(128), dim3(256), 0, stream, out, h0, Wh,
                       hpk, flags);
}